// Round 5
// baseline (22247.746 us; speedup 1.0000x reference)
//
#include <hip/hip_runtime.h>
#include <hip/hip_bf16.h>
#include <cmath>

#define BATCH 128
#define SEQ   512
#define IN_DIM 512
#define HID   1024

typedef __attribute__((ext_vector_type(8))) short short8;
typedef __attribute__((ext_vector_type(4))) float f32x4;

union S8u { int w[4]; short8 s; };

// ---- trunc-trunc bf16x2 split, v_perm-packed: x = hi + lo + eps, |eps|<=2^-16|x|
__device__ __forceinline__ void splitT8(const float* __restrict__ p,
                                        short8& hi, short8& lo) {
    float4 va = *(const float4*)p;
    float4 vb = *(const float4*)(p + 4);
    float q[8] = {va.x, va.y, va.z, va.w, vb.x, vb.y, vb.z, vb.w};
    S8u H, L;
    #pragma unroll
    for (int j = 0; j < 4; ++j) {
        unsigned u0 = __float_as_uint(q[2 * j]);
        unsigned u1 = __float_as_uint(q[2 * j + 1]);
        H.w[j] = __builtin_amdgcn_perm(u1, u0, 0x07060302);  // {hi16(x1),hi16(x0)}
        float r0 = q[2 * j]     - __uint_as_float(u0 & 0xffff0000u);
        float r1 = q[2 * j + 1] - __uint_as_float(u1 & 0xffff0000u);
        L.w[j] = __builtin_amdgcn_perm(__float_as_uint(r1), __float_as_uint(r0),
                                       0x07060302);
    }
    hi = H.s; lo = L.s;
}

// ---- RNE-RNE split: |eps| <= ~2^-17.5 |x| (recurrent path) ----------------
__device__ __forceinline__ unsigned rne_u(float x) {
    unsigned u = __float_as_uint(x);
    return u + 0x7fffu + ((u >> 16) & 1u);   // rounded bf16 in top 16 bits
}
__device__ __forceinline__ void splitR8(const float* __restrict__ p,
                                        short8& hi, short8& lo) {
    float4 va = *(const float4*)p;
    float4 vb = *(const float4*)(p + 4);
    float q[8] = {va.x, va.y, va.z, va.w, vb.x, vb.y, vb.z, vb.w};
    S8u H, L;
    #pragma unroll
    for (int j = 0; j < 4; ++j) {
        unsigned h0 = rne_u(q[2 * j]);
        unsigned h1 = rne_u(q[2 * j + 1]);
        H.w[j] = __builtin_amdgcn_perm(h1, h0, 0x07060302);
        float r0 = q[2 * j]     - __uint_as_float(h0 & 0xffff0000u);
        float r1 = q[2 * j + 1] - __uint_as_float(h1 & 0xffff0000u);
        L.w[j] = __builtin_amdgcn_perm(rne_u(r1), rne_u(r0), 0x07060302);
    }
    hi = H.s; lo = L.s;
}

// ---------------------------------------------------------------------------
// Kernel 1: xw = x @ W_in^T + (b_in+b_lat+bh) -> d_out   (bf16x2, 3-pass MFMA)
// Tile [128m x 64n], K=512, 4 waves, 128 KB LDS. Bijective XCD-chunk swizzle:
// each XCD owns a contiguous mg range -> x slice read once per XCD.
// ---------------------------------------------------------------------------
__global__ __launch_bounds__(256) void gemm_xw(const float* __restrict__ x,
        const float* __restrict__ Wi, const float* __restrict__ bi,
        const float* __restrict__ bl, const float* __restrict__ bhv,
        float* __restrict__ out) {
    __shared__ short8 Bhi[64 * 64];   // [n][g'] 16B granules, 64 KB
    __shared__ short8 Blo[64 * 64];   // 64 KB
    const int bid0 = blockIdx.x;
    const int v = (bid0 & 7) * 1024 + (bid0 >> 3);   // 8192 % 8 == 0: bijective
    const int mg = v >> 4, ng = v & 15;              // 512 x 16
    const int m0 = mg * 128, n0 = ng * 64;
    const int tid = threadIdx.x;

    // stage W_in tile: split inline, XOR granule swizzle g' = g ^ (n&7)
    #pragma unroll
    for (int j = 0; j < 16; ++j) {
        int s = tid + j * 256;            // 4096 granules
        int n = s >> 6, gp = s & 63;
        int g = gp ^ (n & 7);
        short8 hi, lo;
        splitT8(&Wi[(size_t)(n0 + n) * IN_DIM + g * 8], hi, lo);
        Bhi[n * 64 + gp] = hi;
        Blo[n * 64 + gp] = lo;
    }
    __syncthreads();

    const int l = tid & 63, w = tid >> 6;
    const int lr = l & 15, lk = l >> 4;
    f32x4 acc[2][4];
    #pragma unroll
    for (int mi = 0; mi < 2; ++mi)
        #pragma unroll
        for (int nt = 0; nt < 4; ++nt) acc[mi][nt] = (f32x4)0.0f;

    const float* xrow0 = x + (size_t)(m0 + w * 32 + lr) * IN_DIM;
    const float* xrow1 = x + (size_t)(m0 + w * 32 + 16 + lr) * IN_DIM;

    for (int ks = 0; ks < 16; ++ks) {
        int kc = ks * 32 + lk * 8;
        short8 a0h, a0l, a1h, a1l;
        splitT8(xrow0 + kc, a0h, a0l);
        splitT8(xrow1 + kc, a1h, a1l);
        int g = ks * 4 + lk;
        #pragma unroll
        for (int nt = 0; nt < 4; ++nt) {
            int nl = nt * 16 + lr;
            int gp = g ^ (nl & 7);
            short8 bh8 = Bhi[nl * 64 + gp];
            short8 bl8 = Blo[nl * 64 + gp];
            acc[0][nt] = __builtin_amdgcn_mfma_f32_16x16x32_bf16(a0h, bh8, acc[0][nt], 0, 0, 0);
            acc[0][nt] = __builtin_amdgcn_mfma_f32_16x16x32_bf16(a0h, bl8, acc[0][nt], 0, 0, 0);
            acc[0][nt] = __builtin_amdgcn_mfma_f32_16x16x32_bf16(a0l, bh8, acc[0][nt], 0, 0, 0);
            acc[1][nt] = __builtin_amdgcn_mfma_f32_16x16x32_bf16(a1h, bh8, acc[1][nt], 0, 0, 0);
            acc[1][nt] = __builtin_amdgcn_mfma_f32_16x16x32_bf16(a1h, bl8, acc[1][nt], 0, 0, 0);
            acc[1][nt] = __builtin_amdgcn_mfma_f32_16x16x32_bf16(a1l, bh8, acc[1][nt], 0, 0, 0);
        }
    }
    // epilogue: D row = lk*4+r, col = lr per 16x16 tile; add biases
    #pragma unroll
    for (int nt = 0; nt < 4; ++nt) {
        int c = n0 + nt * 16 + lr;
        float bsum = bi[c] + bl[c] + bhv[c];
        #pragma unroll
        for (int mi = 0; mi < 2; ++mi)
            #pragma unroll
            for (int r = 0; r < 4; ++r) {
                int row = m0 + w * 32 + mi * 16 + lk * 4 + r;
                out[(size_t)row * HID + c] = acc[mi][nt][r] + bsum;
            }
    }
}

// ---------------------------------------------------------------------------
// Kernel 2: persistent scan. 256 blocks x 256 threads (4 waves, 1 block/CU).
// Group g = bid&7 (XCD-pin heuristic): batch rows 16g..16g+15 = independent
// RNN. 32 blocks/group; block owns cols n0 = 32*(bid>>3). Wave w = K-slice
// [256w, 256w+256) over BOTH 16-col tiles: W regs = 2x8x(hi,lo) short8 =
// 128 VGPR/lane. Cross-wave K-reduction via 9 KB LDS. h state: RNE-split
// bf16 hi/lo planes ping-pong in ws. Flag-array group barrier (no RMW).
// ---------------------------------------------------------------------------
__global__ __launch_bounds__(256, 1) void rnn_scan(const float* __restrict__ h0,
        const float* __restrict__ Wl, float* __restrict__ out,
        unsigned short* __restrict__ hp0, unsigned short* __restrict__ lp0,
        unsigned short* __restrict__ hp1, unsigned short* __restrict__ lp1,
        unsigned* __restrict__ flags) {
    __shared__ float red[4 * 16 * 36];     // [w][row][col(+4 pad)] = 9.2 KB
    const int bid = blockIdx.x;            // 0..255
    const int g = bid & 7;                 // batch group
    const int slot = bid >> 3;             // 0..31 within group
    const int m0 = g * 16;
    const int n0 = slot * 32;
    const int tid = threadIdx.x;
    const int l = tid & 63, w = tid >> 6;  // wave id 0..3 = K-slice
    const int lr = l & 15, lk = l >> 4;
    unsigned* gf = flags + g * 64;         // 256B-separated per-group flag line

    // ---- W_lat block-slice -> registers (RNE split), once ----
    short8 bhi[2][8], blo[2][8];
    #pragma unroll
    for (int nt = 0; nt < 2; ++nt)
        #pragma unroll
        for (int ks = 0; ks < 8; ++ks)
            splitR8(Wl + (size_t)(n0 + nt * 16 + lr) * HID + w * 256 + ks * 32 + lk * 8,
                    bhi[nt][ks], blo[nt][ks]);

    const size_t prow = (size_t)(m0 + lr) * HID + w * 256;  // A base (planes)
    const int erow = tid >> 3, ecol = (tid & 7) * 4;        // epilogue coords

    for (int t = 0; t < SEQ; ++t) {
        // ---- wait for all 32 blocks of the group to finish step t-1 ----
        if (t > 0) {
            if (tid < 32)
                while (__hip_atomic_load(&gf[tid], __ATOMIC_RELAXED,
                                         __HIP_MEMORY_SCOPE_AGENT) < (unsigned)t)
                    __builtin_amdgcn_s_sleep(1);
            __syncthreads();
            __threadfence();   // acquire h-planes written by other blocks
        }

        // ---- K-slice MFMA ----
        f32x4 acc0 = (f32x4)0.0f, acc1 = (f32x4)0.0f;
        if (t == 0) {
            const float* h0row = h0 + (size_t)(m0 + lr) * HID + w * 256;
            #pragma unroll
            for (int ks = 0; ks < 8; ++ks) {
                short8 ah, al;
                splitR8(h0row + ks * 32 + lk * 8, ah, al);
                acc0 = __builtin_amdgcn_mfma_f32_16x16x32_bf16(ah, bhi[0][ks], acc0, 0, 0, 0);
                acc0 = __builtin_amdgcn_mfma_f32_16x16x32_bf16(ah, blo[0][ks], acc0, 0, 0, 0);
                acc0 = __builtin_amdgcn_mfma_f32_16x16x32_bf16(al, bhi[0][ks], acc0, 0, 0, 0);
                acc1 = __builtin_amdgcn_mfma_f32_16x16x32_bf16(ah, bhi[1][ks], acc1, 0, 0, 0);
                acc1 = __builtin_amdgcn_mfma_f32_16x16x32_bf16(ah, blo[1][ks], acc1, 0, 0, 0);
                acc1 = __builtin_amdgcn_mfma_f32_16x16x32_bf16(al, bhi[1][ks], acc1, 0, 0, 0);
            }
        } else {
            const unsigned short* hrow = ((t & 1) ? hp1 : hp0) + prow;
            const unsigned short* lrow = ((t & 1) ? lp1 : lp0) + prow;
            #pragma unroll
            for (int ks = 0; ks < 8; ++ks) {
                short8 ah = *(const short8*)&hrow[ks * 32 + lk * 8];
                short8 al = *(const short8*)&lrow[ks * 32 + lk * 8];
                acc0 = __builtin_amdgcn_mfma_f32_16x16x32_bf16(ah, bhi[0][ks], acc0, 0, 0, 0);
                acc0 = __builtin_amdgcn_mfma_f32_16x16x32_bf16(ah, blo[0][ks], acc0, 0, 0, 0);
                acc0 = __builtin_amdgcn_mfma_f32_16x16x32_bf16(al, bhi[0][ks], acc0, 0, 0, 0);
                acc1 = __builtin_amdgcn_mfma_f32_16x16x32_bf16(ah, bhi[1][ks], acc1, 0, 0, 0);
                acc1 = __builtin_amdgcn_mfma_f32_16x16x32_bf16(ah, blo[1][ks], acc1, 0, 0, 0);
                acc1 = __builtin_amdgcn_mfma_f32_16x16x32_bf16(al, bhi[1][ks], acc1, 0, 0, 0);
            }
        }

        // ---- stash per-wave partials (each wave owns its red region) ----
        #pragma unroll
        for (int r = 0; r < 4; ++r) {
            red[(w * 16 + lk * 4 + r) * 36 + lr] = acc0[r];
            red[(w * 16 + lk * 4 + r) * 36 + 16 + lr] = acc1[r];
        }
        __syncthreads();

        // ---- reduce 4-way K-split + tanh + write out & next h planes ----
        if (tid < 128) {
            float4 sv = make_float4(0.f, 0.f, 0.f, 0.f);
            #pragma unroll
            for (int w2 = 0; w2 < 4; ++w2) {
                float4 p = *(const float4*)&red[(w2 * 16 + erow) * 36 + ecol];
                sv.x += p.x; sv.y += p.y; sv.z += p.z; sv.w += p.w;
            }
            size_t oidx = ((size_t)(m0 + erow) * SEQ + t) * HID + n0 + ecol;
            float4 xw = *(const float4*)&out[oidx];
            float hv[4] = { tanhf(xw.x + sv.x), tanhf(xw.y + sv.y),
                            tanhf(xw.z + sv.z), tanhf(xw.w + sv.w) };
            *(float4*)&out[oidx] = make_float4(hv[0], hv[1], hv[2], hv[3]);

            unsigned short* hout = (t & 1) ? hp0 : hp1;
            unsigned short* lout = (t & 1) ? lp0 : lp1;
            size_t pidx = (size_t)(m0 + erow) * HID + n0 + ecol;
            ushort4 hq, lq;
            unsigned short* hqp = (unsigned short*)&hq;
            unsigned short* lqp = (unsigned short*)&lq;
            #pragma unroll
            for (int j = 0; j < 4; ++j) {
                unsigned hu = rne_u(hv[j]);
                hqp[j] = (unsigned short)(hu >> 16);
                float rr = hv[j] - __uint_as_float(hu & 0xffff0000u);
                lqp[j] = (unsigned short)(rne_u(rr) >> 16);
            }
            *(ushort4*)&hout[pidx] = hq;
            *(ushort4*)&lout[pidx] = lq;
        }

        // ---- post flag: step t complete (planes + out released) ----
        __threadfence();
        __syncthreads();
        if (tid == 0)
            __hip_atomic_store(&gf[slot], (unsigned)(t + 1), __ATOMIC_RELAXED,
                               __HIP_MEMORY_SCOPE_AGENT);
    }
}

// ---------------------------------------------------------------------------
extern "C" void kernel_launch(void* const* d_in, const int* in_sizes, int n_in,
                              void* d_out, int out_size, void* d_ws, size_t ws_size,
                              hipStream_t stream) {
    const float* x     = (const float*)d_in[0];
    const float* h0    = (const float*)d_in[1];
    const float* W_in  = (const float*)d_in[2];
    const float* b_in  = (const float*)d_in[3];
    const float* W_lat = (const float*)d_in[4];
    const float* b_lat = (const float*)d_in[5];
    const float* bh    = (const float*)d_in[6];
    float* out = (float*)d_out;

    // ws: 2KB flags + 4 x 256KB h planes  (~1.03 MB)
    unsigned char* ws = (unsigned char*)d_ws;
    unsigned*       flags = (unsigned*)(ws);
    unsigned short* hp0 = (unsigned short*)(ws + (size_t)4 * 1024);
    unsigned short* lp0 = (unsigned short*)(ws + (size_t)(4 + 256) * 1024);
    unsigned short* hp1 = (unsigned short*)(ws + (size_t)(4 + 512) * 1024);
    unsigned short* lp1 = (unsigned short*)(ws + (size_t)(4 + 768) * 1024);

    // Phase 1: input projection + biases -> d_out
    gemm_xw<<<8192, 256, 0, stream>>>(x, W_in, b_in, b_lat, bh, out);

    // flags must start at 0 (ws is re-poisoned 0xAA before every timed call)
    hipMemsetAsync(flags, 0, 2048, stream);

    // Phase 2: persistent scan (cooperative: all 256 blocks co-resident)
    void* args[] = { (void*)&h0, (void*)&W_lat, (void*)&out,
                     (void*)&hp0, (void*)&lp0, (void*)&hp1, (void*)&lp1,
                     (void*)&flags };
    hipLaunchCooperativeKernel((void*)rnn_scan, dim3(256), dim3(256), args, 0, stream);
}

// Round 6
// 4036.156 us; speedup vs baseline: 5.5121x; 5.5121x over previous
//
#include <hip/hip_runtime.h>
#include <hip/hip_bf16.h>
#include <cmath>

#define BATCH 128
#define SEQ   512
#define IN_DIM 512
#define HID   1024

typedef __attribute__((ext_vector_type(8))) short short8;
typedef __attribute__((ext_vector_type(4))) float f32x4;

union S8u { int w[4]; short8 s; };

// ---- trunc-trunc bf16x2 split, v_perm-packed: x = hi + lo + eps, |eps|<=2^-16|x|
__device__ __forceinline__ void splitT8(const float* __restrict__ p,
                                        short8& hi, short8& lo) {
    float4 va = *(const float4*)p;
    float4 vb = *(const float4*)(p + 4);
    float q[8] = {va.x, va.y, va.z, va.w, vb.x, vb.y, vb.z, vb.w};
    S8u H, L;
    #pragma unroll
    for (int j = 0; j < 4; ++j) {
        unsigned u0 = __float_as_uint(q[2 * j]);
        unsigned u1 = __float_as_uint(q[2 * j + 1]);
        H.w[j] = __builtin_amdgcn_perm(u1, u0, 0x07060302);  // {hi16(x1),hi16(x0)}
        float r0 = q[2 * j]     - __uint_as_float(u0 & 0xffff0000u);
        float r1 = q[2 * j + 1] - __uint_as_float(u1 & 0xffff0000u);
        L.w[j] = __builtin_amdgcn_perm(__float_as_uint(r1), __float_as_uint(r0),
                                       0x07060302);
    }
    hi = H.s; lo = L.s;
}

// ---- RNE-RNE split: |eps| <= ~2^-17.5 |x| (recurrent path) ----------------
__device__ __forceinline__ unsigned rne_u(float x) {
    unsigned u = __float_as_uint(x);
    return u + 0x7fffu + ((u >> 16) & 1u);   // rounded bf16 in top 16 bits
}
__device__ __forceinline__ void splitR8(const float* __restrict__ p,
                                        short8& hi, short8& lo) {
    float4 va = *(const float4*)p;
    float4 vb = *(const float4*)(p + 4);
    float q[8] = {va.x, va.y, va.z, va.w, vb.x, vb.y, vb.z, vb.w};
    S8u H, L;
    #pragma unroll
    for (int j = 0; j < 4; ++j) {
        unsigned h0 = rne_u(q[2 * j]);
        unsigned h1 = rne_u(q[2 * j + 1]);
        H.w[j] = __builtin_amdgcn_perm(h1, h0, 0x07060302);
        float r0 = q[2 * j]     - __uint_as_float(h0 & 0xffff0000u);
        float r1 = q[2 * j + 1] - __uint_as_float(h1 & 0xffff0000u);
        L.w[j] = __builtin_amdgcn_perm(rne_u(r1), rne_u(r0), 0x07060302);
    }
    hi = H.s; lo = L.s;
}

// ---- agent-coherent (sc1, L3-visible) plane access; no L2 fences needed ----
__device__ __forceinline__ short8 ld_pl(const unsigned short* p) {
    const unsigned long long* q = (const unsigned long long*)p;
    unsigned long long a = __hip_atomic_load(q,     __ATOMIC_RELAXED, __HIP_MEMORY_SCOPE_AGENT);
    unsigned long long b = __hip_atomic_load(q + 1, __ATOMIC_RELAXED, __HIP_MEMORY_SCOPE_AGENT);
    union { unsigned long long u[2]; short8 s; } r;
    r.u[0] = a; r.u[1] = b;
    return r.s;
}
__device__ __forceinline__ void st_pl(unsigned short* p, unsigned long long v) {
    __hip_atomic_store((unsigned long long*)p, v, __ATOMIC_RELAXED, __HIP_MEMORY_SCOPE_AGENT);
}

// ---------------------------------------------------------------------------
// Kernel 1: xw = x @ W_in^T + (b_in+b_lat+bh) -> d_out   (bf16x2, 3-pass MFMA)
// (unchanged from round-4: known-correct; ~0.7 ms, next round's target)
// ---------------------------------------------------------------------------
__global__ __launch_bounds__(256) void gemm_xw(const float* __restrict__ x,
        const float* __restrict__ Wi, const float* __restrict__ bi,
        const float* __restrict__ bl, const float* __restrict__ bhv,
        float* __restrict__ out) {
    __shared__ short8 Bhi[64 * 64];   // [n][g'] 16B granules, 64 KB
    __shared__ short8 Blo[64 * 64];   // 64 KB
    const int bid0 = blockIdx.x;
    const int v = (bid0 & 7) * 1024 + (bid0 >> 3);   // 8192 % 8 == 0: bijective
    const int mg = v >> 4, ng = v & 15;              // 512 x 16
    const int m0 = mg * 128, n0 = ng * 64;
    const int tid = threadIdx.x;

    #pragma unroll
    for (int j = 0; j < 16; ++j) {
        int s = tid + j * 256;            // 4096 granules
        int n = s >> 6, gp = s & 63;
        int g = gp ^ (n & 7);
        short8 hi, lo;
        splitT8(&Wi[(size_t)(n0 + n) * IN_DIM + g * 8], hi, lo);
        Bhi[n * 64 + gp] = hi;
        Blo[n * 64 + gp] = lo;
    }
    __syncthreads();

    const int l = tid & 63, w = tid >> 6;
    const int lr = l & 15, lk = l >> 4;
    f32x4 acc[2][4];
    #pragma unroll
    for (int mi = 0; mi < 2; ++mi)
        #pragma unroll
        for (int nt = 0; nt < 4; ++nt) acc[mi][nt] = (f32x4)0.0f;

    const float* xrow0 = x + (size_t)(m0 + w * 32 + lr) * IN_DIM;
    const float* xrow1 = x + (size_t)(m0 + w * 32 + 16 + lr) * IN_DIM;

    for (int ks = 0; ks < 16; ++ks) {
        int kc = ks * 32 + lk * 8;
        short8 a0h, a0l, a1h, a1l;
        splitT8(xrow0 + kc, a0h, a0l);
        splitT8(xrow1 + kc, a1h, a1l);
        int g = ks * 4 + lk;
        #pragma unroll
        for (int nt = 0; nt < 4; ++nt) {
            int nl = nt * 16 + lr;
            int gp = g ^ (nl & 7);
            short8 bh8 = Bhi[nl * 64 + gp];
            short8 bl8 = Blo[nl * 64 + gp];
            acc[0][nt] = __builtin_amdgcn_mfma_f32_16x16x32_bf16(a0h, bh8, acc[0][nt], 0, 0, 0);
            acc[0][nt] = __builtin_amdgcn_mfma_f32_16x16x32_bf16(a0h, bl8, acc[0][nt], 0, 0, 0);
            acc[0][nt] = __builtin_amdgcn_mfma_f32_16x16x32_bf16(a0l, bh8, acc[0][nt], 0, 0, 0);
            acc[1][nt] = __builtin_amdgcn_mfma_f32_16x16x32_bf16(a1h, bh8, acc[1][nt], 0, 0, 0);
            acc[1][nt] = __builtin_amdgcn_mfma_f32_16x16x32_bf16(a1h, bl8, acc[1][nt], 0, 0, 0);
            acc[1][nt] = __builtin_amdgcn_mfma_f32_16x16x32_bf16(a1l, bh8, acc[1][nt], 0, 0, 0);
        }
    }
    #pragma unroll
    for (int nt = 0; nt < 4; ++nt) {
        int c = n0 + nt * 16 + lr;
        float bsum = bi[c] + bl[c] + bhv[c];
        #pragma unroll
        for (int mi = 0; mi < 2; ++mi)
            #pragma unroll
            for (int r = 0; r < 4; ++r) {
                int row = m0 + w * 32 + mi * 16 + lk * 4 + r;
                out[(size_t)row * HID + c] = acc[mi][nt][r] + bsum;
            }
    }
}

// ---------------------------------------------------------------------------
// Kernel 2: persistent scan. 256 blocks x 256 threads, 1 block/CU.
// Group g = bid&7: batch rows 16g..+15 = independent RNN; 32 blocks/group.
// Block owns cols n0 = 32*(bid>>3); wave w = K-slice [256w,256w+256).
// W_lat slice in 32 NAMED short8 registers/lane (no arrays -> no scratch).
// h planes exchanged via relaxed agent atomics (sc1 -> L3-coherent): NO
// __threadfence / L2 wbinv anywhere. Flag-array barrier per group.
// ---------------------------------------------------------------------------
__global__ __launch_bounds__(256, 1) void rnn_scan(const float* __restrict__ h0,
        const float* __restrict__ Wl, float* __restrict__ out,
        unsigned short* __restrict__ hp0, unsigned short* __restrict__ lp0,
        unsigned short* __restrict__ hp1, unsigned short* __restrict__ lp1,
        unsigned* __restrict__ flags) {
    __shared__ float red[4 * 16 * 36];     // [w][row][col(+4 pad)] = 9.2 KB
    const int bid = blockIdx.x;            // 0..255
    const int g = bid & 7;                 // batch group (XCD-pin heuristic)
    const int slot = bid >> 3;             // 0..31 within group
    const int m0 = g * 16;
    const int n0 = slot * 32;
    const int tid = threadIdx.x;
    const int l = tid & 63, w = tid >> 6;  // wave id 0..3 = K-slice
    const int lr = l & 15, lk = l >> 4;
    unsigned* gf = flags + g * 64;         // 256B-separated per-group flag line

    // ---- W_lat slice -> 32 NAMED short8 registers (RNE split), once ----
#define DECL_W(ks) short8 wh0_##ks, wl0_##ks, wh1_##ks, wl1_##ks;
    DECL_W(0) DECL_W(1) DECL_W(2) DECL_W(3)
    DECL_W(4) DECL_W(5) DECL_W(6) DECL_W(7)
#undef DECL_W
    {
        const float* w0 = Wl + (size_t)(n0 + lr) * HID + w * 256 + lk * 8;
        const float* w1 = Wl + (size_t)(n0 + 16 + lr) * HID + w * 256 + lk * 8;
#define LOAD_W(ks) splitR8(w0 + ks * 32, wh0_##ks, wl0_##ks); \
                   splitR8(w1 + ks * 32, wh1_##ks, wl1_##ks);
        LOAD_W(0) LOAD_W(1) LOAD_W(2) LOAD_W(3)
        LOAD_W(4) LOAD_W(5) LOAD_W(6) LOAD_W(7)
#undef LOAD_W
    }

    const size_t prow = (size_t)(m0 + lr) * HID + w * 256;  // A base (planes)
    const int erow = tid >> 3, ecol = (tid & 7) * 4;        // epilogue coords

#define MFMA6(AH, AL, KS)                                                        \
    acc0 = __builtin_amdgcn_mfma_f32_16x16x32_bf16(AH, wh0_##KS, acc0, 0, 0, 0); \
    acc0 = __builtin_amdgcn_mfma_f32_16x16x32_bf16(AH, wl0_##KS, acc0, 0, 0, 0); \
    acc0 = __builtin_amdgcn_mfma_f32_16x16x32_bf16(AL, wh0_##KS, acc0, 0, 0, 0); \
    acc1 = __builtin_amdgcn_mfma_f32_16x16x32_bf16(AH, wh1_##KS, acc1, 0, 0, 0); \
    acc1 = __builtin_amdgcn_mfma_f32_16x16x32_bf16(AH, wl1_##KS, acc1, 0, 0, 0); \
    acc1 = __builtin_amdgcn_mfma_f32_16x16x32_bf16(AL, wh1_##KS, acc1, 0, 0, 0);

    for (int t = 0; t < SEQ; ++t) {
        // ---- wait: all 32 blocks of the group finished step t-1 ----
        if (t > 0) {
            if (tid < 32)
                while (__hip_atomic_load(&gf[tid], __ATOMIC_RELAXED,
                                         __HIP_MEMORY_SCOPE_AGENT) < (unsigned)t)
                    __builtin_amdgcn_s_sleep(1);
            __syncthreads();   // compiler+hw barrier; plane loads stay below
        }

        // ---- K-slice MFMA ----
        f32x4 acc0 = (f32x4)0.0f, acc1 = (f32x4)0.0f;
        if (t == 0) {
            const float* h0row = h0 + (size_t)(m0 + lr) * HID + w * 256;
#define KSTEP0(KS) { short8 ah, al; splitR8(h0row + KS * 32 + lk * 8, ah, al); \
                     MFMA6(ah, al, KS) }
            KSTEP0(0) KSTEP0(1) KSTEP0(2) KSTEP0(3)
            KSTEP0(4) KSTEP0(5) KSTEP0(6) KSTEP0(7)
#undef KSTEP0
        } else {
            const unsigned short* hrow = ((t & 1) ? hp1 : hp0) + prow;
            const unsigned short* lrow = ((t & 1) ? lp1 : lp0) + prow;
#define KSTEP(KS) { short8 ah = ld_pl(hrow + KS * 32 + lk * 8);  \
                    short8 al = ld_pl(lrow + KS * 32 + lk * 8);  \
                    MFMA6(ah, al, KS) }
            KSTEP(0) KSTEP(1) KSTEP(2) KSTEP(3)
            KSTEP(4) KSTEP(5) KSTEP(6) KSTEP(7)
#undef KSTEP
        }

        // ---- stash per-wave partials (each wave owns its red region) ----
        #pragma unroll
        for (int r = 0; r < 4; ++r) {
            red[(w * 16 + lk * 4 + r) * 36 + lr] = acc0[r];
            red[(w * 16 + lk * 4 + r) * 36 + 16 + lr] = acc1[r];
        }
        __syncthreads();

        // ---- reduce 4-way K-split + tanh + write out & next h planes ----
        if (tid < 128) {
            float4 sv = make_float4(0.f, 0.f, 0.f, 0.f);
            #pragma unroll
            for (int w2 = 0; w2 < 4; ++w2) {
                float4 p = *(const float4*)&red[(w2 * 16 + erow) * 36 + ecol];
                sv.x += p.x; sv.y += p.y; sv.z += p.z; sv.w += p.w;
            }
            size_t oidx = ((size_t)(m0 + erow) * SEQ + t) * HID + n0 + ecol;
            float4 xw = *(const float4*)&out[oidx];
            float hv[4] = { tanhf(xw.x + sv.x), tanhf(xw.y + sv.y),
                            tanhf(xw.z + sv.z), tanhf(xw.w + sv.w) };
            *(float4*)&out[oidx] = make_float4(hv[0], hv[1], hv[2], hv[3]);

            unsigned long long hq = 0ull, lq = 0ull;
            #pragma unroll
            for (int j = 0; j < 4; ++j) {
                unsigned hu = rne_u(hv[j]);
                hq |= (unsigned long long)(hu >> 16) << (16 * j);
                float rr = hv[j] - __uint_as_float(hu & 0xffff0000u);
                lq |= (unsigned long long)(rne_u(rr) >> 16) << (16 * j);
            }
            unsigned short* hout = (t & 1) ? hp0 : hp1;
            unsigned short* lout = (t & 1) ? lp0 : lp1;
            size_t pidx = (size_t)(m0 + erow) * HID + n0 + ecol;
            st_pl(&hout[pidx], hq);
            st_pl(&lout[pidx], lq);
        }

        // ---- post flag: planes at L3 (vmcnt drained), then release slot ----
        asm volatile("s_waitcnt vmcnt(0)" ::: "memory");
        __syncthreads();
        if (tid == 0)
            __hip_atomic_store(&gf[slot], (unsigned)(t + 1), __ATOMIC_RELAXED,
                               __HIP_MEMORY_SCOPE_AGENT);
    }
#undef MFMA6
}

// ---------------------------------------------------------------------------
extern "C" void kernel_launch(void* const* d_in, const int* in_sizes, int n_in,
                              void* d_out, int out_size, void* d_ws, size_t ws_size,
                              hipStream_t stream) {
    const float* x     = (const float*)d_in[0];
    const float* h0    = (const float*)d_in[1];
    const float* W_in  = (const float*)d_in[2];
    const float* b_in  = (const float*)d_in[3];
    const float* W_lat = (const float*)d_in[4];
    const float* b_lat = (const float*)d_in[5];
    const float* bh    = (const float*)d_in[6];
    float* out = (float*)d_out;

    // ws: 2KB flags + 4 x 256KB h planes  (~1.03 MB)
    unsigned char* ws = (unsigned char*)d_ws;
    unsigned*       flags = (unsigned*)(ws);
    unsigned short* hp0 = (unsigned short*)(ws + (size_t)4 * 1024);
    unsigned short* lp0 = (unsigned short*)(ws + (size_t)(4 + 256) * 1024);
    unsigned short* hp1 = (unsigned short*)(ws + (size_t)(4 + 512) * 1024);
    unsigned short* lp1 = (unsigned short*)(ws + (size_t)(4 + 768) * 1024);

    // Phase 1: input projection + biases -> d_out
    gemm_xw<<<8192, 256, 0, stream>>>(x, W_in, b_in, b_lat, bh, out);

    // flags must start at 0 (ws is re-poisoned 0xAA before every timed call)
    hipMemsetAsync(flags, 0, 2048, stream);

    // Phase 2: persistent scan (cooperative: all 256 blocks co-resident)
    void* args[] = { (void*)&h0, (void*)&W_lat, (void*)&out,
                     (void*)&hp0, (void*)&lp0, (void*)&hp1, (void*)&lp1,
                     (void*)&flags };
    hipLaunchCooperativeKernel((void*)rnn_scan, dim3(256), dim3(256), args, 0, stream);
}